// Round 22
// baseline (203.538 us; speedup 1.0000x reference)
//
#include <hip/hip_runtime.h>

#define GLOBAL_AS __attribute__((address_space(1)))
#define LDS_AS    __attribute__((address_space(3)))

typedef int   i32x4  __attribute__((ext_vector_type(4)));
typedef int   i32x8  __attribute__((ext_vector_type(8)));
typedef float f32x4  __attribute__((ext_vector_type(4)));

// ---------- fp4 e2m1 encode: values {0,.5,1,1.5,2,3,4,6}, round-to-nearest ----------
__device__ __forceinline__ unsigned int fp4_nib(float v) {
    float a = fabsf(v);
    unsigned int m;
    if      (a < 0.25f) m = 0;
    else if (a < 0.75f) m = 1;
    else if (a < 1.25f) m = 2;
    else if (a < 1.75f) m = 3;
    else if (a < 2.5f)  m = 4;
    else if (a < 3.5f)  m = 5;
    else if (a < 5.0f)  m = 6;
    else                m = 7;
    return m | (v < 0.0f ? 8u : 0u);
}

// ---------- kernel 1: fused L2 normalize -> fp4 of (x * 32 / ||row||) ----------
// out rows: 768 elts = 384 B (2 elts/byte, elt 2i = low nibble).
__global__ __launch_bounds__(256) void l2norm_fp4_kernel(const float* __restrict__ audio,
                                                         const float* __restrict__ visual,
                                                         unsigned char* __restrict__ out) {
    const int gw = blockIdx.x * 4 + (threadIdx.x >> 6);  // global row 0..24575
    const int l  = threadIdx.x & 63;
    const float* src = (gw < 16384) ? (audio + (size_t)gw * 768)
                                    : (visual + ((size_t)gw - 16384) * 768);
    const float4* p = (const float4*)src;
    float4 a = p[l], b = p[l + 64], c = p[l + 128];
    float ss = a.x * a.x + a.y * a.y + a.z * a.z + a.w * a.w
             + b.x * b.x + b.y * b.y + b.z * b.z + b.w * b.w
             + c.x * c.x + c.y * c.y + c.z * c.z + c.w * c.w;
#pragma unroll
    for (int m = 1; m < 64; m <<= 1) ss += __shfl_xor(ss, m, 64);
    const float s = 32.0f / fmaxf(sqrtf(ss), 1e-12f);
    unsigned short* o = (unsigned short*)(out + (size_t)gw * 384);
    unsigned short u0 = (unsigned short)(fp4_nib(a.x * s) | (fp4_nib(a.y * s) << 4) |
                                         (fp4_nib(a.z * s) << 8) | (fp4_nib(a.w * s) << 12));
    unsigned short u1 = (unsigned short)(fp4_nib(b.x * s) | (fp4_nib(b.y * s) << 4) |
                                         (fp4_nib(b.z * s) << 8) | (fp4_nib(b.w * s) << 12));
    unsigned short u2 = (unsigned short)(fp4_nib(c.x * s) | (fp4_nib(c.y * s) << 4) |
                                         (fp4_nib(c.z * s) << 8) | (fp4_nib(c.w * s) << 12));
    o[l] = u0; o[l + 64] = u1; o[l + 128] = u2;
}

// ---------- kernel 2: 64x64-tile MX-fp4 GEMM, SINGLE-WAVE blocks, ZERO barriers ----
// The R6-R21 series pinned at ~20% MfmaUtil: 2 s_barriers/K-tile convoying 4
// lockstep waves. A single-wave block needs NO barriers: its own global_load_lds
// results are visible after vmcnt; WAR on the double buffer is ordered by a
// per-wave lgkmcnt(0) before re-staging. Every wave is an independent stream.
// Tile 64 audio rows x 64 visual cols (quarter clip), full wave-tile MFMA as
// before (16x mfma_scale_16x16x128 per BK=128 K-tile, 6 tiles).
// LDS 16 KiB (2 bufs x {A 4K + B 4K}) -> 10 blocks/CU, all desynchronized.
// Frag-slot layout (per 8 KB buf): A @0: granule g = fi*64 + lane (fi 0..3)
// holds (row = fi*16 + (lane&15), K-bytes ((lane>>4)&3)*16 .. +15); B @4096 same
// over the 64 V-rows. Read = ONE lane-linear ds_read_b128/frag (0 conflicts).
// Stage chunk q: dest q*1024 + tid*16 -> source row = q*16 + (tid&15),
// kb = ((tid>>4)&3)*16 (wave = 16 rows x contiguous 64 B = 16 full lines).
// Schedule per K-tile kt (buf=kt&1): vmcnt(8) [kt landed, kt+1's 8 in flight] ->
// ds_reads + 16 MFMA -> lgkmcnt(0) -> STAGE(buf, kt+2). No s_barrier anywhere.
// MFMA: cbsz=4, blgp=4 (FP4), payload regs [0:3] (upper undef, R19-verified).
// NOTE: (64,4) cap = 128 regs = measured demand of this exact fragment/acc
// structure (R21: no spill at cap 128). Keep fb[4]+single-fav live-set shape.

__device__ __forceinline__ i32x8 rd_frag4(const char* p) {
    i32x4 d = *(const i32x4*)(p);
    return __builtin_shufflevector(d, d, 0, 1, 2, 3, -1, -1, -1, -1);
}

#define STAGE(BUF, KT) do {                                                           \
    const size_t _ko = (size_t)(KT) * 64;                                             \
    char* _d = smem + (BUF) * 8192 + tid * 16;                                        \
    __builtin_amdgcn_global_load_lds((GLOBAL_AS void*)(aStage + _ko),                 \
                                     (LDS_AS void*)(_d), 16, 0, 0);                   \
    __builtin_amdgcn_global_load_lds((GLOBAL_AS void*)(aStage + _ko + 6144),          \
                                     (LDS_AS void*)(_d + 1024), 16, 0, 0);            \
    __builtin_amdgcn_global_load_lds((GLOBAL_AS void*)(aStage + _ko + 12288),         \
                                     (LDS_AS void*)(_d + 2048), 16, 0, 0);            \
    __builtin_amdgcn_global_load_lds((GLOBAL_AS void*)(aStage + _ko + 18432),         \
                                     (LDS_AS void*)(_d + 3072), 16, 0, 0);            \
    __builtin_amdgcn_global_load_lds((GLOBAL_AS void*)(vStage + _ko),                 \
                                     (LDS_AS void*)(_d + 4096), 16, 0, 0);            \
    __builtin_amdgcn_global_load_lds((GLOBAL_AS void*)(vStage + _ko + 6144),          \
                                     (LDS_AS void*)(_d + 5120), 16, 0, 0);            \
    __builtin_amdgcn_global_load_lds((GLOBAL_AS void*)(vStage + _ko + 12288),         \
                                     (LDS_AS void*)(_d + 6144), 16, 0, 0);            \
    __builtin_amdgcn_global_load_lds((GLOBAL_AS void*)(vStage + _ko + 18432),         \
                                     (LDS_AS void*)(_d + 7168), 16, 0, 0);            \
  } while (0)

__global__ __launch_bounds__(64, 4) void gemm_max_kernel(
    const unsigned char* __restrict__ A, const unsigned char* __restrict__ V,
    float* __restrict__ rowquarter) {
    __shared__ __align__(1024) char smem[16384];

    const int tid = threadIdx.x;     // 0..63 (one wave)
    const int lr  = tid & 15;
    const int lg  = tid >> 4;        // 0..3

    // O1 streaming block order + XCD swizzle (32768 blocks, %8==0 -> bijective).
    // colBlk inner within an XCD -> V (3 MB fp4) stays L2-resident per XCD.
    const int bx  = blockIdx.x;
    const int swz = (bx & 7) * 4096 + (bx >> 3);
    const int rowBlk = swz >> 7;     // 0..255
    const int colBlk = swz & 127;    // 0..127 (clip = colBlk>>2)
    const size_t aRow0 = (size_t)rowBlk * 64;
    const size_t vRow0 = (size_t)colBlk * 64;

    // staging source (frag-slot inverse). Row stride 384 B (fp4); chunk q = +16 rows.
    const unsigned char* aStage = A + (aRow0 + (tid & 15)) * 384 + ((tid >> 4) & 3) * 16;
    const unsigned char* vStage = V + (vRow0 + (tid & 15)) * 384 + ((tid >> 4) & 3) * 16;

    // reader bases (within buf): one b128 per frag at fi*1024 + tid*16
    const int aBase = tid * 16;          // + buf*8192 + mi*1024
    const int bBase = 4096 + tid * 16;   // + buf*8192 + ni*1024

    f32x4 acc[4][4];
#pragma unroll
    for (int i = 0; i < 4; ++i)
#pragma unroll
        for (int j = 0; j < 4; ++j) {
            acc[i][j][0] = 0.0f; acc[i][j][1] = 0.0f;
            acc[i][j][2] = 0.0f; acc[i][j][3] = 0.0f;
        }

    // prologue: stage tiles 0 and 1 (16 loads outstanding)
    STAGE(0, 0);
    STAGE(1, 1);

#pragma unroll 1
    for (int kt = 0; kt < 6; ++kt) {
        const int buf = kt & 1;
        // own tile-kt loads landed (keep tile kt+1's 8 in flight); no barrier —
        // single wave, its vmcnt certifies its own LDS contents.
        if (kt < 5) asm volatile("s_waitcnt vmcnt(8)" ::: "memory");
        else        asm volatile("s_waitcnt vmcnt(0)" ::: "memory");
        __builtin_amdgcn_sched_barrier(0);

        const char* aB = smem + buf * 8192 + aBase;
        const char* bB = smem + buf * 8192 + bBase;
        i32x8 fb[4];
#pragma unroll
        for (int ni = 0; ni < 4; ++ni) fb[ni] = rd_frag4(bB + ni * 1024);
#pragma unroll
        for (int mi = 0; mi < 4; ++mi) {
            const i32x8 fav = rd_frag4(aB + mi * 1024);
#pragma unroll
            for (int ni = 0; ni < 4; ++ni)
                acc[mi][ni] = __builtin_amdgcn_mfma_scale_f32_16x16x128_f8f6f4(
                    fav, fb[ni], acc[mi][ni], 4, 4, 0, 0x7F7F7F7F, 0, 0x7F7F7F7F);
        }

        // WAR fence: all ds_reads of buf complete before re-staging it (per-wave)
        if (kt < 4) {
            asm volatile("s_waitcnt lgkmcnt(0)" ::: "memory");
            __builtin_amdgcn_sched_barrier(0);
            STAGE(buf, kt + 2);
        }
    }

    // epilogue: fused row-max over this block's 64 visual cols; wave-local,
    // direct global write. C/D layout (16x16): col = lane&15, row = (lane>>4)*4 + reg.
    float* outBase = rowquarter + (size_t)colBlk * 16384 + aRow0;
#pragma unroll
    for (int mi = 0; mi < 4; ++mi) {
#pragma unroll
        for (int j = 0; j < 4; ++j) {
            float m = fmaxf(fmaxf(acc[mi][0][j], acc[mi][1][j]),
                            fmaxf(acc[mi][2][j], acc[mi][3][j]));
            m = fmaxf(m, __shfl_xor(m, 1, 64));
            m = fmaxf(m, __shfl_xor(m, 2, 64));
            m = fmaxf(m, __shfl_xor(m, 4, 64));
            m = fmaxf(m, __shfl_xor(m, 8, 64));
            if (lr == 0) outBase[mi * 16 + lg * 4 + j] = m;
        }
    }
}

// ---------- kernel 3: combine 4 quarter-clips (max) + mean over 512 rows ----------
// folds 1/temp (x10), 1/512 mean, and 1/1024 fp4 pre-scale compensation (32*32).
__global__ __launch_bounds__(256) void reduce_mean_kernel(const float* __restrict__ rq,
                                                          float* __restrict__ clip) {
    const int b = blockIdx.x >> 5;
    const int c = blockIdx.x & 31;
    const int t = threadIdx.x;
    const float* p = rq + (size_t)(c * 4) * 16384 + (size_t)b * 512;
    float s = 0.0f;
#pragma unroll
    for (int r = 0; r < 2; ++r) {
        const int o = t + r * 256;
        float m = fmaxf(fmaxf(p[o], p[o + 16384]),
                        fmaxf(p[o + 32768], p[o + 49152]));
        s += m;
    }
#pragma unroll
    for (int m = 1; m < 64; m <<= 1) s += __shfl_xor(s, m, 64);
    __shared__ float wsum[4];
    if ((t & 63) == 0) wsum[t >> 6] = s;
    __syncthreads();
    if (t == 0)
        clip[b * 32 + c] = (wsum[0] + wsum[1] + wsum[2] + wsum[3]) * (1.0f / (51.2f * 1024.0f));
}

// ---------- kernel 4: log-softmax both ways on 32x32 + scalar loss ----------
__global__ __launch_bounds__(1024) void finalize_kernel(const float* __restrict__ clip,
                                                        float* __restrict__ out) {
    __shared__ float cs[32][33];
    __shared__ float rlse[32], clse[32];
    const int t = threadIdx.x;
    const int b = t >> 5, c = t & 31;
    cs[b][c] = clip[b * 32 + c];
    __syncthreads();
    if (t < 32) {
        float mx = -1e30f;
        for (int j = 0; j < 32; ++j) mx = fmaxf(mx, cs[t][j]);
        float s = 0.0f;
        for (int j = 0; j < 32; ++j) s += expf(cs[t][j] - mx);
        rlse[t] = mx + logf(s);
    } else if (t < 64) {
        const int cc = t - 32;
        float mx = -1e30f;
        for (int j = 0; j < 32; ++j) mx = fmaxf(mx, cs[j][cc]);
        float s = 0.0f;
        for (int j = 0; j < 32; ++j) s += expf(cs[j][cc] - mx);
        clse[cc] = mx + logf(s);
    }
    __syncthreads();
    if (t == 0) {
        float L = 0.0f;
        for (int i = 0; i < 32; ++i)
            L += -0.5f * (2.0f * cs[i][i] - rlse[i] - clse[i]);
        out[0] = L * (1.0f / 32.0f);
    }
}

extern "C" void kernel_launch(void* const* d_in, const int* in_sizes, int n_in,
                              void* d_out, int out_size, void* d_ws, size_t ws_size,
                              hipStream_t stream) {
    const float* audio  = (const float*)d_in[0];   // (32, 512, 768) f32
    const float* visual = (const float*)d_in[1];   // (32, 256, 768) f32

    unsigned char* aN = (unsigned char*)d_ws;                   // 16384*384 fp4
    unsigned char* vN = aN + (size_t)16384 * 384;               // 8192*384 fp4
    float* rowquarter = (float*)(vN + (size_t)8192 * 384);      // 128*16384 f32
    float* clip       = rowquarter + (size_t)128 * 16384;       // 1024 f32
    float* out        = (float*)d_out;

    l2norm_fp4_kernel<<<6144, 256, 0, stream>>>(audio, visual, aN);
    gemm_max_kernel<<<32768, 64, 0, stream>>>(aN, vN, rowquarter);
    reduce_mean_kernel<<<1024, 256, 0, stream>>>(rowquarter, clip);
    finalize_kernel<<<1, 1024, 0, stream>>>(clip, out);
}

// Round 23
// 119.607 us; speedup vs baseline: 1.7017x; 1.7017x over previous
//
#include <hip/hip_runtime.h>

#define GLOBAL_AS __attribute__((address_space(1)))
#define LDS_AS    __attribute__((address_space(3)))

typedef int   i32x4  __attribute__((ext_vector_type(4)));
typedef int   i32x8  __attribute__((ext_vector_type(8)));
typedef float f32x4  __attribute__((ext_vector_type(4)));

// ---------- fp4 e2m1 encode: values {0,.5,1,1.5,2,3,4,6}, round-to-nearest ----------
__device__ __forceinline__ unsigned int fp4_nib(float v) {
    float a = fabsf(v);
    unsigned int m;
    if      (a < 0.25f) m = 0;
    else if (a < 0.75f) m = 1;
    else if (a < 1.25f) m = 2;
    else if (a < 1.75f) m = 3;
    else if (a < 2.5f)  m = 4;
    else if (a < 3.5f)  m = 5;
    else if (a < 5.0f)  m = 6;
    else                m = 7;
    return m | (v < 0.0f ? 8u : 0u);
}

// ---------- kernel 1: fused L2 normalize -> fp4 of (x * 32 / ||row||) ----------
__global__ __launch_bounds__(256) void l2norm_fp4_kernel(const float* __restrict__ audio,
                                                         const float* __restrict__ visual,
                                                         unsigned char* __restrict__ out) {
    const int gw = blockIdx.x * 4 + (threadIdx.x >> 6);  // global row 0..24575
    const int l  = threadIdx.x & 63;
    const float* src = (gw < 16384) ? (audio + (size_t)gw * 768)
                                    : (visual + ((size_t)gw - 16384) * 768);
    const float4* p = (const float4*)src;
    float4 a = p[l], b = p[l + 64], c = p[l + 128];
    float ss = a.x * a.x + a.y * a.y + a.z * a.z + a.w * a.w
             + b.x * b.x + b.y * b.y + b.z * b.z + b.w * b.w
             + c.x * c.x + c.y * c.y + c.z * c.z + c.w * c.w;
#pragma unroll
    for (int m = 1; m < 64; m <<= 1) ss += __shfl_xor(ss, m, 64);
    const float s = 32.0f / fmaxf(sqrtf(ss), 1e-12f);
    unsigned short* o = (unsigned short*)(out + (size_t)gw * 384);
    unsigned short u0 = (unsigned short)(fp4_nib(a.x * s) | (fp4_nib(a.y * s) << 4) |
                                         (fp4_nib(a.z * s) << 8) | (fp4_nib(a.w * s) << 12));
    unsigned short u1 = (unsigned short)(fp4_nib(b.x * s) | (fp4_nib(b.y * s) << 4) |
                                         (fp4_nib(b.z * s) << 8) | (fp4_nib(b.w * s) << 12));
    unsigned short u2 = (unsigned short)(fp4_nib(c.x * s) | (fp4_nib(c.y * s) << 4) |
                                         (fp4_nib(c.z * s) << 8) | (fp4_nib(c.w * s) << 12));
    o[l] = u0; o[l + 64] = u1; o[l + 128] = u2;
}

// ---------- kernel 2: V-IN-REGISTERS MX-fp4 GEMM, LDS-port-relief structure --------
// Diagnosis (R6-R22): LDS read port was the binding resource (~1540 cy demand vs
// 1295 cy tile wall) -> MfmaUtil pinned ~20% regardless of schedule. Fix: V is
// REGISTER-resident (wave's 64 cols x full K=768 fp4 = 96 VGPRs, loaded once);
// only A flows through LDS, and each staged A-slab is shared by all 4 waves.
// LDS traffic per FLOP drops ~4x -> MFMA-bound regime.
// Block = 256 thr (4 waves), owns clip c (wave w: cols c*256 + w*64 ..+63) and
// rows rowBase..rowBase+255 (4 iterations x 64 rows, A dbuf'd full-K slabs).
// A LDS slab (24.5 KB): granule g = kt*256 + fi*64 + lane holds
//   (row = fi*16 + (lane&15), kb = kt*64 + ((lane>>4)&3)*16 .. +15)
// -> A-frag read = ONE lane-linear ds_read_b128 @ kt*4096 + mi*1024 + l*16 (0 confl).
// Stage chunk q (0..5): dest q*4096 + tid*16 <- src row ((tid>>6)&3)*16 + (tid&15),
//   kb = q*64 + ((tid>>4)&3)*16  (wave = 16 rows x contiguous 64 B, coalesced).
// V-frag (ni,kt): lane l: addr (vCol0 + ni*16 + (l&15))*384 + kt*64 + (l>>4)*16.
// Schedule per iteration it (buf=it&1): vmcnt(6) -> s_barrier -> 24 ds_reads +
// 96 MFMA -> pm writes -> s_barrier -> STAGE(buf, it+2) + pm reduce/global write.
// Block order: bx -> x=bx&7 (XCD), idx=bx>>3; clip = x*4 + (idx&3) [clip-inner ->
// V L2-resident per XCD], rowBase = (idx>>2)*256 [A streamed once per XCD].
// MFMA: cbsz=4, blgp=4 (FP4), payload regs [0:3] (upper undef, R19-verified).
// REGS: vb 96 + acc 64 (AGPR) + temps ~40 ~= 200; (256,2) cap 256. TRIPWIRE:
// WRITE_SIZE blowup = spill (R5/R15 mechanism) -> revert to R18.

__device__ __forceinline__ i32x8 to8(i32x4 d) {
    return __builtin_shufflevector(d, d, 0, 1, 2, 3, -1, -1, -1, -1);
}

#define STAGE_A(BUF, IT) do {                                                         \
    const unsigned char* _s = aStage + (size_t)(IT) * 24576;                          \
    char* _d = smem + (BUF) * 24576 + tid * 16;                                       \
    __builtin_amdgcn_global_load_lds((GLOBAL_AS void*)(_s),                           \
                                     (LDS_AS void*)(_d), 16, 0, 0);                   \
    __builtin_amdgcn_global_load_lds((GLOBAL_AS void*)(_s + 64),                      \
                                     (LDS_AS void*)(_d + 4096), 16, 0, 0);            \
    __builtin_amdgcn_global_load_lds((GLOBAL_AS void*)(_s + 128),                     \
                                     (LDS_AS void*)(_d + 8192), 16, 0, 0);            \
    __builtin_amdgcn_global_load_lds((GLOBAL_AS void*)(_s + 192),                     \
                                     (LDS_AS void*)(_d + 12288), 16, 0, 0);           \
    __builtin_amdgcn_global_load_lds((GLOBAL_AS void*)(_s + 256),                     \
                                     (LDS_AS void*)(_d + 16384), 16, 0, 0);           \
    __builtin_amdgcn_global_load_lds((GLOBAL_AS void*)(_s + 320),                     \
                                     (LDS_AS void*)(_d + 20480), 16, 0, 0);           \
  } while (0)

__global__ __launch_bounds__(256, 2) void gemm_max_kernel(
    const unsigned char* __restrict__ A, const unsigned char* __restrict__ V,
    float* __restrict__ rowmax) {
    __shared__ __align__(1024) char smem[50176];  // 2 x 24576 A-dbuf + 1024 pm

    const int tid = threadIdx.x;
    const int l   = tid & 63;
    const int wid = tid >> 6;      // 0..3 : 64-col group of the clip
    const int lr  = l & 15;
    const int lg  = l >> 4;        // 0..3

    const int bx  = blockIdx.x;    // 2048 blocks
    const int x   = bx & 7;        // XCD
    const int idx = bx >> 3;       // 0..255
    const int clip    = x * 4 + (idx & 3);      // 0..31 (clip-inner per XCD)
    const int rowBase = (idx >> 2) * 256;       // 0..16128
    const size_t vCol0 = (size_t)clip * 256 + wid * 64;

    // V -> registers: vb[ni][kt], static indexing only (rule #20)
    i32x4 vb[4][6];
#pragma unroll
    for (int ni = 0; ni < 4; ++ni)
#pragma unroll
        for (int kt = 0; kt < 6; ++kt)
            vb[ni][kt] = *(const i32x4*)(V + (vCol0 + ni * 16 + lr) * 384
                                           + kt * 64 + lg * 16);

    // A staging source (frag-slot inverse; row stride 384 B fp4)
    const unsigned char* aStage = A + ((size_t)rowBase + ((tid >> 6) & 3) * 16
                                       + (tid & 15)) * 384 + ((tid >> 4) & 3) * 16;

    float* pm = (float*)(smem + 49152);  // [64 rows][4 wid]

    // prologue: stage iteration-0 and -1 A-slabs (12 loads/thread outstanding)
    STAGE_A(0, 0);
    STAGE_A(1, 1);

#pragma unroll 1
    for (int it = 0; it < 4; ++it) {
        const int buf = it & 1;
        // own slab landed; next slab's 6 loads stay in flight (V-loads older ->
        // also drained; compiler adds its own waits for vb uses)
        if (it < 3) asm volatile("s_waitcnt vmcnt(6)" ::: "memory");
        else        asm volatile("s_waitcnt vmcnt(0)" ::: "memory");
        __builtin_amdgcn_sched_barrier(0);
        __builtin_amdgcn_s_barrier();
        __builtin_amdgcn_sched_barrier(0);

        f32x4 acc[4][4];
#pragma unroll
        for (int i = 0; i < 4; ++i)
#pragma unroll
            for (int j = 0; j < 4; ++j) {
                acc[i][j][0] = 0.0f; acc[i][j][1] = 0.0f;
                acc[i][j][2] = 0.0f; acc[i][j][3] = 0.0f;
            }

        const char* aB = smem + buf * 24576 + l * 16;
#pragma unroll
        for (int kt = 0; kt < 6; ++kt) {
            i32x8 fa[4];
#pragma unroll
            for (int mi = 0; mi < 4; ++mi)
                fa[mi] = to8(*(const i32x4*)(aB + kt * 4096 + mi * 1024));
#pragma unroll
            for (int mi = 0; mi < 4; ++mi)
#pragma unroll
                for (int ni = 0; ni < 4; ++ni)
                    acc[mi][ni] = __builtin_amdgcn_mfma_scale_f32_16x16x128_f8f6f4(
                        fa[mi], to8(vb[ni][kt]), acc[mi][ni],
                        4, 4, 0, 0x7F7F7F7F, 0, 0x7F7F7F7F);
        }

        // per-iteration epilogue: row-max over this wave's 64 cols -> pm
        // C/D layout (16x16): col = lane&15, row = (lane>>4)*4 + reg (m89)
#pragma unroll
        for (int mi = 0; mi < 4; ++mi) {
#pragma unroll
            for (int j = 0; j < 4; ++j) {
                float m = fmaxf(fmaxf(acc[mi][0][j], acc[mi][1][j]),
                                fmaxf(acc[mi][2][j], acc[mi][3][j]));
                m = fmaxf(m, __shfl_xor(m, 1, 64));
                m = fmaxf(m, __shfl_xor(m, 2, 64));
                m = fmaxf(m, __shfl_xor(m, 4, 64));
                m = fmaxf(m, __shfl_xor(m, 8, 64));
                if (lr == 0) pm[(mi * 16 + lg * 4 + j) * 4 + wid] = m;
            }
        }
        __builtin_amdgcn_sched_barrier(0);
        __builtin_amdgcn_s_barrier();   // pm visible; all A-reads of buf complete
        __builtin_amdgcn_sched_barrier(0);
        if (it < 2) STAGE_A(buf, it + 2);
        if (tid < 64) {
            float m = fmaxf(fmaxf(pm[tid * 4], pm[tid * 4 + 1]),
                            fmaxf(pm[tid * 4 + 2], pm[tid * 4 + 3]));
            rowmax[(size_t)clip * 16384 + rowBase + it * 64 + tid] = m;
        }
        // next iteration's entry barrier orders these pm reads vs next pm writes
    }
}

// ---------- kernel 3: mean over 512 audio rows -> clip_sims[32][32] ----------
// folds 1/temp (x10), 1/512 mean, and 1/1024 fp4 pre-scale compensation (32*32).
__global__ __launch_bounds__(256) void reduce_mean_kernel(const float* __restrict__ rm,
                                                          float* __restrict__ clip) {
    const int b = blockIdx.x >> 5;
    const int c = blockIdx.x & 31;
    const int t = threadIdx.x;
    const float* p = rm + (size_t)c * 16384 + (size_t)b * 512;
    float s = p[t] + p[t + 256];
#pragma unroll
    for (int m = 1; m < 64; m <<= 1) s += __shfl_xor(s, m, 64);
    __shared__ float wsum[4];
    if ((t & 63) == 0) wsum[t >> 6] = s;
    __syncthreads();
    if (t == 0)
        clip[b * 32 + c] = (wsum[0] + wsum[1] + wsum[2] + wsum[3]) * (1.0f / (51.2f * 1024.0f));
}

// ---------- kernel 4: log-softmax both ways on 32x32 + scalar loss ----------
__global__ __launch_bounds__(1024) void finalize_kernel(const float* __restrict__ clip,
                                                        float* __restrict__ out) {
    __shared__ float cs[32][33];
    __shared__ float rlse[32], clse[32];
    const int t = threadIdx.x;
    const int b = t >> 5, c = t & 31;
    cs[b][c] = clip[b * 32 + c];
    __syncthreads();
    if (t < 32) {
        float mx = -1e30f;
        for (int j = 0; j < 32; ++j) mx = fmaxf(mx, cs[t][j]);
        float s = 0.0f;
        for (int j = 0; j < 32; ++j) s += expf(cs[t][j] - mx);
        rlse[t] = mx + logf(s);
    } else if (t < 64) {
        const int cc = t - 32;
        float mx = -1e30f;
        for (int j = 0; j < 32; ++j) mx = fmaxf(mx, cs[j][cc]);
        float s = 0.0f;
        for (int j = 0; j < 32; ++j) s += expf(cs[j][cc] - mx);
        clse[cc] = mx + logf(s);
    }
    __syncthreads();
    if (t == 0) {
        float L = 0.0f;
        for (int i = 0; i < 32; ++i)
            L += -0.5f * (2.0f * cs[i][i] - rlse[i] - clse[i]);
        out[0] = L * (1.0f / 32.0f);
    }
}

extern "C" void kernel_launch(void* const* d_in, const int* in_sizes, int n_in,
                              void* d_out, int out_size, void* d_ws, size_t ws_size,
                              hipStream_t stream) {
    const float* audio  = (const float*)d_in[0];   // (32, 512, 768) f32
    const float* visual = (const float*)d_in[1];   // (32, 256, 768) f32

    unsigned char* aN = (unsigned char*)d_ws;                   // 16384*384 fp4
    unsigned char* vN = aN + (size_t)16384 * 384;               // 8192*384 fp4
    float* rowmax = (float*)(vN + (size_t)8192 * 384);          // 32*16384 f32
    float* clip   = rowmax + (size_t)32 * 16384;                // 1024 f32
    float* out    = (float*)d_out;

    l2norm_fp4_kernel<<<6144, 256, 0, stream>>>(audio, visual, aN);
    gemm_max_kernel<<<2048, 256, 0, stream>>>(aN, vN, rowmax);
    reduce_mean_kernel<<<1024, 256, 0, stream>>>(rowmax, clip);
    finalize_kernel<<<1, 1024, 0, stream>>>(clip, out);
}